// Round 5
// baseline (808.250 us; speedup 1.0000x reference)
//
#include <hip/hip_runtime.h>

// SlotAttention on MI355X (gfx950).
// Never materialize k/v:
//   logits[n,s] = rstd_n*(x_n . qg_s) + (rstd_n*mu_n)*c_s + d_s   (qg = g*(Wk q)/16, MFMA bf16)
//   Y[s,i]      = sum_n attn[n,s]*rstd_n*x[n,i]                   (MFMA: A=a2^T, B=x columns)
//   updates     = (g*(Y-S1) + b*S0)/(S0+1e-8) @ Wv                (tiny MFMA)
// R5: attn occupancy fix — 256-thr blocks, grid 32x64 (5+ blocks/CU), 32-row groups,
//     redundant phase A per wave with wave-private a2^T scratch (2 barriers/group, no
//     cross-wave hazards), pass0 LN stats via MFMA. Slot back to R3's 1024-thr form.

typedef unsigned short u16;
typedef __attribute__((ext_vector_type(8))) short bf16x8;
typedef __attribute__((ext_vector_type(4))) float f32x4;

#define MFMA16(a, b, c) __builtin_amdgcn_mfma_f32_16x16x32_bf16((a), (b), (c), 0, 0, 0)

__device__ __forceinline__ u16 f2bf(float f) {
  union { float f; unsigned u; } v; v.f = f;
  unsigned r = (v.u + 0x7fffu + ((v.u >> 16) & 1u)) >> 16;
  return (u16)r;
}
__device__ __forceinline__ float sigm(float x) { return 1.f / (1.f + __expf(-x)); }
__device__ __forceinline__ float tanh_f(float x) { return 1.f - 2.f / (1.f + __expf(2.f * x)); }

// ---------------------------------------------------------------- prep: LDS-tiled transpose + casts
__global__ __launch_bounds__(256) void prep_kernel(
    const float* __restrict__ Wq, const float* __restrict__ Wk, const float* __restrict__ Wv,
    const float* __restrict__ wih, const float* __restrict__ whh,
    const float* __restrict__ w1, const float* __restrict__ w2,
    u16* __restrict__ wkB, u16* __restrict__ wqT, u16* __restrict__ wvT,
    u16* __restrict__ wihB, u16* __restrict__ whhB, u16* __restrict__ w1T, u16* __restrict__ w2T) {
  const int bid = blockIdx.x;
  const int tid = threadIdx.x;
  if (bid < 160) {
    __shared__ float tile[64][65];
    const float* src; u16* dst; int R, C, t;
    if (bid < 16)      { src = Wq; dst = wqT; R = 256;  C = 256;  t = bid; }
    else if (bid < 32) { src = Wv; dst = wvT; R = 256;  C = 256;  t = bid - 16; }
    else if (bid < 96) { src = w1; dst = w1T; R = 1024; C = 256;  t = bid - 32; }
    else               { src = w2; dst = w2T; R = 256;  C = 1024; t = bid - 96; }
    const int tilesJ = C >> 6;
    const int i0 = (t / tilesJ) * 64, j0 = (t % tilesJ) * 64;
    const int c = tid & 63, r0 = tid >> 6;
#pragma unroll
    for (int rr = 0; rr < 16; rr++) {
      int row = rr * 4 + r0;
      tile[row][c] = src[(size_t)(j0 + row) * R + i0 + c];
    }
    __syncthreads();
#pragma unroll
    for (int rr = 0; rr < 16; rr++) {
      int row = rr * 4 + r0;
      dst[(size_t)(i0 + row) * C + j0 + c] = f2bf(tile[c][row]);
    }
  } else {
    int gid = (bid - 160) * 256 + tid;
    for (int i4 = gid; i4 < 114688; i4 += 64 * 256) {
      int i = i4 * 4;
      const float* s; u16* d; int off;
      if (i < 65536) { s = Wk; d = wkB; off = i; }
      else if (i < 262144) { s = wih; d = wihB; off = i - 65536; }
      else { s = whh; d = whhB; off = i - 262144; }
      float4 v = *reinterpret_cast<const float4*>(s + off);
      unsigned lo = (unsigned)f2bf(v.x) | ((unsigned)f2bf(v.y) << 16);
      unsigned hi = (unsigned)f2bf(v.z) | ((unsigned)f2bf(v.w) << 16);
      *reinterpret_cast<uint2*>(d + off) = make_uint2(lo, hi);
    }
  }
}

// ---------------------------------------------------------------- per-wave LN of one row, rows 8..15 zeroed
__device__ __forceinline__ void ln_row16(const float (*src)[264], u16 (*dst)[264],
                                         const float* __restrict__ g, const float* __restrict__ bb,
                                         int wave, int lane) {
  int row = wave;
  if (row < 8) {
    float4 v = *reinterpret_cast<const float4*>(&src[row][lane * 4]);
    float s = v.x + v.y + v.z + v.w;
    float sq = v.x * v.x + v.y * v.y + v.z * v.z + v.w * v.w;
#pragma unroll
    for (int m = 1; m < 64; m <<= 1) { s += __shfl_xor(s, m); sq += __shfl_xor(sq, m); }
    float mu = s * (1.f / 256.f);
    float var = sq * (1.f / 256.f) - mu * mu;
    float rstd = rsqrtf(fmaxf(var, 0.f) + 1e-5f);
    float4 gg = *reinterpret_cast<const float4*>(&g[lane * 4]);
    float4 bv = *reinterpret_cast<const float4*>(&bb[lane * 4]);
    unsigned lo = (unsigned)f2bf((v.x - mu) * rstd * gg.x + bv.x) |
                  ((unsigned)f2bf((v.y - mu) * rstd * gg.y + bv.y) << 16);
    unsigned hi = (unsigned)f2bf((v.z - mu) * rstd * gg.z + bv.z) |
                  ((unsigned)f2bf((v.w - mu) * rstd * gg.w + bv.w) << 16);
    *reinterpret_cast<uint2*>(&dst[row][lane * 4]) = make_uint2(lo, hi);
  } else if (row < 16) {
    *reinterpret_cast<uint2*>(&dst[row][lane * 4]) = make_uint2(0, 0);
  }
}

// ---------------------------------------------------------------- slot kernel: one block (1024 thr, 16 waves) per batch
__global__ __launch_bounds__(1024, 4) void slot_kernel(
    float* __restrict__ slots, u16* __restrict__ qg, float* __restrict__ cd,
    const float* __restrict__ wsY, const float* __restrict__ wsS,
    const u16* __restrict__ wvT, const u16* __restrict__ wihB, const u16* __restrict__ whhB,
    const u16* __restrict__ w1T, const u16* __restrict__ w2T, const u16* __restrict__ wqT,
    const u16* __restrict__ wkB,
    const float* __restrict__ bih, const float* __restrict__ bhh,
    const float* __restrict__ b1v, const float* __restrict__ b2v,
    const float* __restrict__ g_in, const float* __restrict__ b_in,
    const float* __restrict__ g_s, const float* __restrict__ b_s,
    const float* __restrict__ g_m, const float* __restrict__ b_m,
    const float* __restrict__ s_mu, const float* __restrict__ s_ls,
    const float* __restrict__ noise,
    float* __restrict__ d_out, int do_update) {
  __shared__ alignas(16) char pool[58368];
  u16 (*h_lds)[1032] = reinterpret_cast<u16(*)[1032]>(pool);            // 33024 (P5->P6)
  u16 (*u_lds)[264] = reinterpret_cast<u16(*)[264]>(pool);              // alias h (P1->P2)
  u16 (*uv_lds)[264] = reinterpret_cast<u16(*)[264]>(pool + 8448);      // alias h (P2->P3)
  u16 (*sb_lds)[264] = reinterpret_cast<u16(*)[264]>(pool + 16896);     // alias h (P0->P3)
  u16 (*m_lds)[264] = reinterpret_cast<u16(*)[264]>(pool + 33024);      // 8448
  float (*ns_lds)[264] = reinterpret_cast<float(*)[264]>(pool + 41472); // 16896
  u16 (*q_lds)[264] = reinterpret_cast<u16(*)[264]>(pool + 41472);      // alias ns (P8->P9)
  __shared__ float sS0[16], sS1[16], sInv[16];
  __shared__ float redq[16][4][4][2];

  const int b = blockIdx.x;
  const int tid = threadIdx.x;
  const int lane = tid & 63, wave = tid >> 6;
  const int quad = lane >> 4, col = lane & 15;
  const int i256 = tid & 255, s4 = tid >> 8;
  const f32x4 vzero = {0.f, 0.f, 0.f, 0.f};

  if (do_update) {
    // P0: reduce S partials over 32 chunks; stage slots as bf16
    if (tid < 16) {
      float S0 = 0.f, S1 = 0.f;
      if (tid < 8) {
        for (int c = 0; c < 32; c++) {
          S0 += wsS[((b * 32 + c) * 8 + tid) * 2 + 0];
          S1 += wsS[((b * 32 + c) * 8 + tid) * 2 + 1];
        }
      }
      sS0[tid] = S0; sS1[tid] = S1; sInv[tid] = 1.f / (S0 + 1e-8f);
    }
#pragma unroll
    for (int r = 0; r < 4; r++) {
      int s = s4 + r * 4;
      sb_lds[s][i256] = (s < 8) ? f2bf(slots[(size_t)(b * 8 + s) * 256 + i256]) : (u16)0;
    }
    __syncthreads();
    // P1: u_hat
    {
      float gv = g_in[i256], bv = b_in[i256];
#pragma unroll
      for (int r = 0; r < 4; r++) {
        int s = s4 + r * 4;
        if (s < 8) {
          float y = 0.f;
#pragma unroll
          for (int c = 0; c < 32; c++) y += wsY[((size_t)((b * 32 + c) * 8 + s)) * 256 + i256];
          u_lds[s][i256] = f2bf((gv * (y - sS1[s]) + bv * sS0[s]) * sInv[s]);
        } else {
          u_lds[s][i256] = 0;
        }
      }
    }
    __syncthreads();
    // P2: updates_v = u_hat @ Wv (one tile per wave)
    {
      bf16x8 af[8];
#pragma unroll
      for (int k = 0; k < 8; k++)
        af[k] = *reinterpret_cast<const bf16x8*>(&u_lds[col][k * 32 + quad * 8]);
      int ct = wave;
      f32x4 acc = vzero;
#pragma unroll
      for (int k = 0; k < 8; k++) {
        bf16x8 bf = *reinterpret_cast<const bf16x8*>(wvT + (size_t)(ct * 16 + col) * 256 + k * 32 + quad * 8);
        acc = MFMA16(af[k], bf, acc);
      }
#pragma unroll
      for (int r = 0; r < 4; r++) {
        int s = quad * 4 + r;
        uv_lds[s][ct * 16 + col] = (s < 8) ? f2bf(acc[r]) : (u16)0;
      }
    }
    __syncthreads();
    // P3: gi/gh GEMMs + GRU elementwise -> ns_lds (one d-tile per wave)
    {
      bf16x8 afu[8], afs[8];
#pragma unroll
      for (int k = 0; k < 8; k++) {
        afu[k] = *reinterpret_cast<const bf16x8*>(&uv_lds[col][k * 32 + quad * 8]);
        afs[k] = *reinterpret_cast<const bf16x8*>(&sb_lds[col][k * 32 + quad * 8]);
      }
      int d = wave * 16 + col;
      f32x4 a_ir = vzero, a_iz = vzero, a_in = vzero, a_hr = vzero, a_hz = vzero, a_hn = vzero;
#pragma unroll
      for (int k = 0; k < 8; k++) {
        int ko = k * 32 + quad * 8;
        a_ir = MFMA16(afu[k], *reinterpret_cast<const bf16x8*>(wihB + (size_t)(d)*256 + ko), a_ir);
        a_iz = MFMA16(afu[k], *reinterpret_cast<const bf16x8*>(wihB + (size_t)(256 + d) * 256 + ko), a_iz);
        a_in = MFMA16(afu[k], *reinterpret_cast<const bf16x8*>(wihB + (size_t)(512 + d) * 256 + ko), a_in);
        a_hr = MFMA16(afs[k], *reinterpret_cast<const bf16x8*>(whhB + (size_t)(d)*256 + ko), a_hr);
        a_hz = MFMA16(afs[k], *reinterpret_cast<const bf16x8*>(whhB + (size_t)(256 + d) * 256 + ko), a_hz);
        a_hn = MFMA16(afs[k], *reinterpret_cast<const bf16x8*>(whhB + (size_t)(512 + d) * 256 + ko), a_hn);
      }
      float bihr = bih[d], bihz = bih[256 + d], bihn = bih[512 + d];
      float bhhr = bhh[d], bhhz = bhh[256 + d], bhhn = bhh[512 + d];
#pragma unroll
      for (int r = 0; r < 4; r++) {
        int s = quad * 4 + r;
        float rg = sigm(a_ir[r] + bihr + a_hr[r] + bhhr);
        float zg = sigm(a_iz[r] + bihz + a_hz[r] + bhhz);
        float ng = tanh_f(a_in[r] + bihn + rg * (a_hn[r] + bhhn));
        float prev = (s < 8) ? slots[(size_t)(b * 8 + s) * 256 + d] : 0.f;
        float ns = (1.f - zg) * ng + zg * prev;
        ns_lds[s][d] = (s < 8) ? ns : 0.f;
      }
    }
    __syncthreads();
    // P4: LN_m -> m_lds
    ln_row16(ns_lds, m_lds, g_m, b_m, wave, lane);
    __syncthreads();
    // P5: mlp1 -> h_lds (relu), 4 tiles per wave
    {
      bf16x8 af[8];
#pragma unroll
      for (int k = 0; k < 8; k++)
        af[k] = *reinterpret_cast<const bf16x8*>(&m_lds[col][k * 32 + quad * 8]);
      for (int cc = 0; cc < 4; cc++) {
        int ct = wave * 4 + cc;
        f32x4 acc = vzero;
#pragma unroll
        for (int k = 0; k < 8; k++) {
          bf16x8 bf = *reinterpret_cast<const bf16x8*>(w1T + (size_t)(ct * 16 + col) * 256 + k * 32 + quad * 8);
          acc = MFMA16(af[k], bf, acc);
        }
        float bb = b1v[ct * 16 + col];
#pragma unroll
        for (int r = 0; r < 4; r++) {
          int s = quad * 4 + r;
          float h = fmaxf(acc[r] + bb, 0.f);
          h_lds[s][ct * 16 + col] = (s < 8) ? f2bf(h) : (u16)0;
        }
      }
    }
    __syncthreads();
    // P6: mlp2 + residual -> new slots (one tile per wave)
    {
      int ct = wave;
      f32x4 acc = vzero;
      for (int k = 0; k < 32; k++) {
        bf16x8 af = *reinterpret_cast<const bf16x8*>(&h_lds[col][k * 32 + quad * 8]);
        bf16x8 bf = *reinterpret_cast<const bf16x8*>(w2T + (size_t)(ct * 16 + col) * 1024 + k * 32 + quad * 8);
        acc = MFMA16(af, bf, acc);
      }
      int d = ct * 16 + col;
      float bb = b2v[d];
#pragma unroll
      for (int r = 0; r < 4; r++) {
        int s = quad * 4 + r;
        if (s < 8) {
          float fin = ns_lds[s][d] + acc[r] + bb;
          slots[(size_t)(b * 8 + s) * 256 + d] = fin;
          d_out[(size_t)(b * 8 + s) * 256 + d] = fin;
          ns_lds[s][d] = fin;
        }
      }
    }
    __syncthreads();
  } else {
    // init: slots = mu + exp(ls)*noise
#pragma unroll
    for (int r = 0; r < 4; r++) {
      int s = s4 + r * 4;
      float v = 0.f;
      if (s < 8) {
        v = s_mu[i256] + __expf(s_ls[i256]) * noise[(size_t)(b * 8 + s) * 256 + i256];
        slots[(size_t)(b * 8 + s) * 256 + i256] = v;
      }
      ns_lds[s][i256] = v;
    }
    __syncthreads();
  }

  // ---- TAIL: qg/cd for next attention pass ----
  ln_row16(ns_lds, m_lds, g_s, b_s, wave, lane);
  __syncthreads();
  // P8: q = s_n @ Wq -> q_lds (one tile per wave)
  {
    bf16x8 af[8];
#pragma unroll
    for (int k = 0; k < 8; k++)
      af[k] = *reinterpret_cast<const bf16x8*>(&m_lds[col][k * 32 + quad * 8]);
    int ct = wave;
    f32x4 acc = vzero;
#pragma unroll
    for (int k = 0; k < 8; k++) {
      bf16x8 bf = *reinterpret_cast<const bf16x8*>(wqT + (size_t)(ct * 16 + col) * 256 + k * 32 + quad * 8);
      acc = MFMA16(af[k], bf, acc);
    }
#pragma unroll
    for (int r = 0; r < 4; r++) {
      int s = quad * 4 + r;
      q_lds[s][ct * 16 + col] = (s < 8) ? f2bf(acc[r]) : (u16)0;
    }
  }
  __syncthreads();
  // P9: qk = q @ Wk-as-B; qg = g*qk/16; c = -sum qg; d = sum b*qk/16
  {
    bf16x8 af[8];
#pragma unroll
    for (int k = 0; k < 8; k++)
      af[k] = *reinterpret_cast<const bf16x8*>(&q_lds[col][k * 32 + quad * 8]);
    float cacc[4] = {0.f, 0.f, 0.f, 0.f}, dacc[4] = {0.f, 0.f, 0.f, 0.f};
    int ct = wave;
    f32x4 acc = vzero;
#pragma unroll
    for (int k = 0; k < 8; k++) {
      bf16x8 bf = *reinterpret_cast<const bf16x8*>(wkB + (size_t)(ct * 16 + col) * 256 + k * 32 + quad * 8);
      acc = MFMA16(af[k], bf, acc);
    }
    int i = ct * 16 + col;
    float gi_ = g_in[i] * 0.0625f, bi_ = b_in[i] * 0.0625f;
#pragma unroll
    for (int r = 0; r < 4; r++) {
      int s = quad * 4 + r;
      float qkv = acc[r];
      float qgv = (s < 8) ? gi_ * qkv : 0.f;
      qg[(size_t)(b * 16 + s) * 256 + i] = f2bf(qgv);
      cacc[r] -= qgv;
      dacc[r] += (s < 8) ? bi_ * qkv : 0.f;
    }
#pragma unroll
    for (int r = 0; r < 4; r++) {
#pragma unroll
      for (int m = 1; m < 16; m <<= 1) {
        cacc[r] += __shfl_xor(cacc[r], m);
        dacc[r] += __shfl_xor(dacc[r], m);
      }
    }
    if (col == 0) {
#pragma unroll
      for (int r = 0; r < 4; r++) {
        redq[wave][quad][r][0] = cacc[r];
        redq[wave][quad][r][1] = dacc[r];
      }
    }
    __syncthreads();
    if (tid < 16) {
      int qd = tid >> 2, r = tid & 3;
      float c = 0.f, dd = 0.f;
      for (int w = 0; w < 16; w++) { c += redq[w][qd][r][0]; dd += redq[w][qd][r][1]; }
      cd[(b * 16 + tid) * 2 + 0] = c;
      cd[(b * 16 + tid) * 2 + 1] = dd;
    }
  }
}

// ---------------------------------------------------------------- attention kernel
// grid (32 chunks, 64 batches), 256 threads (4 waves). Each block: 128 n's in 4 groups of 32.
// Phase A redundant on all waves (a2^T in wave-private LDS scratch, no A->B barrier).
// PASS 0: read fp32 x, write xb (bf16) + stats2 (LN stats via MFMA). PASS 1: read xb + stats2.
template <int PASS>
__global__ __launch_bounds__(256, 5) void attn_kernel(
    const float* __restrict__ x, u16* __restrict__ xb, float2* __restrict__ stats2,
    const u16* __restrict__ qg, const float* __restrict__ cd,
    float* __restrict__ out, float* __restrict__ wsY, float* __restrict__ wsS) {
  __shared__ alignas(16) u16 x_lds[32][280];   // pad 280: phase-A b128 2-way banks
  __shared__ alignas(16) u16 a2s[4][16][40];   // wave-private a2^T scratch
  __shared__ float2 stats_lds[32];

  const int chunk = blockIdx.x, b = blockIdx.y;
  const int tid = threadIdx.x;
  const int lane = tid & 63, wave = tid >> 6;   // 4 waves
  const int quad = lane >> 4, col = lane & 15;

  const float2 cdv = *reinterpret_cast<const float2*>(cd + (b * 16 + col) * 2);

  f32x4 Yacc[4];
#pragma unroll
  for (int cc = 0; cc < 4; cc++) Yacc[cc] = {0.f, 0.f, 0.f, 0.f};
  float s0a = 0.f, s1a = 0.f;
  float* out_attn = out + 131072;

  for (int g = 0; g < 4; g++) {
    const int nb = chunk * 128 + g * 32;
    __syncthreads();  // prior group's phase B done with x_lds
    // ---- staging: each wave loads its 8 rows ----
    if (PASS == 0) {
#pragma unroll
      for (int p = 0; p < 8; p++) {
        const int row = wave * 8 + p;
        float4 v = *reinterpret_cast<const float4*>(x + (size_t)(b * 4096 + nb + row) * 256 + lane * 4);
        unsigned lo = (unsigned)f2bf(v.x) | ((unsigned)f2bf(v.y) << 16);
        unsigned hi = (unsigned)f2bf(v.z) | ((unsigned)f2bf(v.w) << 16);
        *reinterpret_cast<uint2*>(&x_lds[row][lane * 4]) = make_uint2(lo, hi);
        *reinterpret_cast<uint2*>(xb + (size_t)(b * 4096 + nb + row) * 256 + lane * 4) = make_uint2(lo, hi);
      }
    } else {
#pragma unroll
      for (int p = 0; p < 8; p++) {
        const int row = wave * 8 + p;
        *reinterpret_cast<uint2*>(&x_lds[row][lane * 4]) =
            *reinterpret_cast<const uint2*>(xb + (size_t)(b * 4096 + nb + row) * 256 + lane * 4);
      }
      if (tid < 32) stats_lds[tid] = stats2[(size_t)b * 4096 + nb + tid];
    }
    __syncthreads();

    // ---- phase A (ALL waves, redundant): 2 row-tiles of 16 ----
    bf16x8 bfrag[8];
#pragma unroll
    for (int k = 0; k < 8; k++)
      bfrag[k] = *reinterpret_cast<const bf16x8*>(qg + (size_t)(b * 16 + col) * 256 + k * 32 + quad * 8);
#pragma unroll
    for (int t = 0; t < 2; t++) {
      bf16x8 af[8];
#pragma unroll
      for (int k = 0; k < 8; k++)
        af[k] = *reinterpret_cast<const bf16x8*>(&x_lds[t * 16 + col][k * 32 + quad * 8]);
      f32x4 acc = {0.f, 0.f, 0.f, 0.f};
#pragma unroll
      for (int k = 0; k < 8; k++) acc = MFMA16(af[k], bfrag[k], acc);

      float rmx[4], rmy[4];
      if (PASS == 0) {
        const short one_bf = (short)0x3F80;
        bf16x8 ones8 = {one_bf, one_bf, one_bf, one_bf, one_bf, one_bf, one_bf, one_bf};
        f32x4 accS = {0.f, 0.f, 0.f, 0.f}, accG = {0.f, 0.f, 0.f, 0.f};
#pragma unroll
        for (int k = 0; k < 8; k++) {
          accS = MFMA16(af[k], ones8, accS);
          accG = MFMA16(af[k], af[k], accG);
        }
#pragma unroll
        for (int r = 0; r < 4; r++) {
          float sq = __shfl(accG[r], (quad << 4) + quad * 4 + r);
          float mu = accS[r] * (1.f / 256.f);
          float var = sq * (1.f / 256.f) - mu * mu;
          float rstd = rsqrtf(fmaxf(var, 0.f) + 1e-5f);
          rmx[r] = rstd; rmy[r] = rstd * mu;
        }
        if (wave == 0 && col == 0) {
#pragma unroll
          for (int r = 0; r < 4; r++)
            stats2[(size_t)b * 4096 + nb + t * 16 + quad * 4 + r] = make_float2(rmx[r], rmy[r]);
        }
      } else {
#pragma unroll
        for (int r = 0; r < 4; r++) {
          float2 rm = stats_lds[t * 16 + quad * 4 + r];
          rmx[r] = rm.x; rmy[r] = rm.y;
        }
      }
      float at[4];
#pragma unroll
      for (int r = 0; r < 4; r++) {
        float lg = rmx[r] * acc[r] + rmy[r] * cdv.x + cdv.y;
        float mx = lg;
        mx = fmaxf(mx, __shfl_xor(mx, 1));
        mx = fmaxf(mx, __shfl_xor(mx, 2));
        mx = fmaxf(mx, __shfl_xor(mx, 4));
        float e = __expf(lg - mx);
        float sm = e;
        sm += __shfl_xor(sm, 1); sm += __shfl_xor(sm, 2); sm += __shfl_xor(sm, 4);
        at[r] = e / sm;
      }
      if (col < 8) {
#pragma unroll
        for (int r = 0; r < 4; r++)
          a2s[wave][col][t * 16 + quad * 4 + r] = f2bf(at[r] * rmx[r]);
        if (wave == 0) {
#pragma unroll
          for (int r = 0; r < 4; r++) {
            out_attn[(size_t)(b * 8 + col) * 4096 + nb + t * 16 + quad * 4 + r] = at[r];
            s0a += at[r];
            s1a += at[r] * rmy[r];
          }
        }
      }
    }
    // ---- phase B: Y[s][i] += a2^T @ x, one K=32 MFMA per i-tile (wave-private scratch) ----
    {
      bf16x8 afa = *reinterpret_cast<const bf16x8*>(&a2s[wave][col][quad * 8]);
#pragma unroll
      for (int cc = 0; cc < 4; cc++) {
        const int ib = (wave * 4 + cc) * 16 + col;
        union { short s[8]; bf16x8 v; } bx;
#pragma unroll
        for (int j = 0; j < 8; j++) bx.s[j] = (short)x_lds[quad * 8 + j][ib];
        Yacc[cc] = MFMA16(afa, bx.v, Yacc[cc]);
      }
    }
  }
  // ---- epilogue ----
  if (quad < 2) {
#pragma unroll
    for (int cc = 0; cc < 4; cc++) {
      int i = (wave * 4 + cc) * 16 + col;
#pragma unroll
      for (int r = 0; r < 4; r++) {
        int s = quad * 4 + r;
        wsY[(size_t)((b * 32 + chunk) * 8 + s) * 256 + i] = Yacc[cc][r];
      }
    }
  }
  s0a += __shfl_xor(s0a, 16); s0a += __shfl_xor(s0a, 32);
  s1a += __shfl_xor(s1a, 16); s1a += __shfl_xor(s1a, 32);
  if (wave == 0 && lane < 8) {
    wsS[((b * 32 + chunk) * 8 + lane) * 2 + 0] = s0a;
    wsS[((b * 32 + chunk) * 8 + lane) * 2 + 1] = s1a;
  }
}

// ---------------------------------------------------------------- launch
extern "C" void kernel_launch(void* const* d_in, const int* in_sizes, int n_in,
                              void* d_out, int out_size, void* d_ws, size_t ws_size,
                              hipStream_t stream) {
  const float* inputs = (const float*)d_in[0];
  const float* noise = (const float*)d_in[1];
  const float* s_mu = (const float*)d_in[2];
  const float* s_ls = (const float*)d_in[3];
  const float* g_in = (const float*)d_in[4];
  const float* b_in = (const float*)d_in[5];
  const float* g_s = (const float*)d_in[6];
  const float* b_s = (const float*)d_in[7];
  const float* g_m = (const float*)d_in[8];
  const float* b_m = (const float*)d_in[9];
  const float* Wq = (const float*)d_in[10];
  const float* Wk = (const float*)d_in[11];
  const float* Wv = (const float*)d_in[12];
  const float* wih = (const float*)d_in[13];
  const float* whh = (const float*)d_in[14];
  const float* bih = (const float*)d_in[15];
  const float* bhh = (const float*)d_in[16];
  const float* w1 = (const float*)d_in[17];
  const float* b1v = (const float*)d_in[18];
  const float* w2 = (const float*)d_in[19];
  const float* b2v = (const float*)d_in[20];
  float* out = (float*)d_out;

  size_t o = 0;
  auto take = [&](size_t bytes) {
    void* p = (char*)d_ws + o;
    o += (bytes + 255) & ~(size_t)255;
    return p;
  };
  float* slots = (float*)take((size_t)64 * 8 * 256 * 4);
  u16* qg = (u16*)take((size_t)64 * 16 * 256 * 2);
  float* cd = (float*)take((size_t)64 * 16 * 2 * 4);
  float* wsY = (float*)take((size_t)64 * 32 * 8 * 256 * 4);
  float* wsS = (float*)take((size_t)64 * 32 * 8 * 2 * 4);
  u16* wkB = (u16*)take((size_t)65536 * 2);
  u16* wqT = (u16*)take((size_t)65536 * 2);
  u16* wvT = (u16*)take((size_t)65536 * 2);
  u16* wihB = (u16*)take((size_t)196608 * 2);
  u16* whhB = (u16*)take((size_t)196608 * 2);
  u16* w1T = (u16*)take((size_t)262144 * 2);
  u16* w2T = (u16*)take((size_t)262144 * 2);
  u16* xb = (u16*)take((size_t)64 * 4096 * 256 * 2);
  float2* stats2 = (float2*)take((size_t)64 * 4096 * 8);

  prep_kernel<<<224, 256, 0, stream>>>(Wq, Wk, Wv, wih, whh, w1, w2,
                                       wkB, wqT, wvT, wihB, whhB, w1T, w2T);
  slot_kernel<<<64, 1024, 0, stream>>>(slots, qg, cd, wsY, wsS,
                                       wvT, wihB, whhB, w1T, w2T, wqT, wkB,
                                       bih, bhh, b1v, b2v,
                                       g_in, b_in, g_s, b_s, g_m, b_m,
                                       s_mu, s_ls, noise, out, 0);
  for (int it = 0; it < 3; it++) {
    if (it == 0)
      attn_kernel<0><<<dim3(32, 64), 256, 0, stream>>>(inputs, xb, stats2, qg, cd, out, wsY, wsS);
    else
      attn_kernel<1><<<dim3(32, 64), 256, 0, stream>>>(inputs, xb, stats2, qg, cd, out, wsY, wsS);
    slot_kernel<<<64, 1024, 0, stream>>>(slots, qg, cd, wsY, wsS,
                                         wvT, wihB, whhB, w1T, w2T, wqT, wkB,
                                         bih, bhh, b1v, b2v,
                                         g_in, b_in, g_s, b_s, g_m, b_m,
                                         s_mu, s_ls, noise, out, 1);
  }
}

// Round 6
// 778.811 us; speedup vs baseline: 1.0378x; 1.0378x over previous
//
#include <hip/hip_runtime.h>

// SlotAttention on MI355X (gfx950).
// Never materialize k/v:
//   logits[n,s] = rstd_n*(x_n . qg_s) + (rstd_n*mu_n)*c_s + d_s   (qg = g*(Wk q)/16, MFMA bf16)
//   Y[s,i]      = sum_n attn[n,s]*rstd_n*x[n,i]                   (MFMA: A=a2^T, B=x columns)
//   updates     = (g*(Y-S1) + b*S0)/(S0+1e-8) @ Wv                (tiny MFMA)
// R6: pass0 split into pure-streaming xcvt (fp32->bf16 + stats); attn runs 3x reading xb
//     with double-buffered LDS staging, ONE barrier/group, hoisted qg fragments.

typedef unsigned short u16;
typedef __attribute__((ext_vector_type(8))) short bf16x8;
typedef __attribute__((ext_vector_type(4))) float f32x4;

#define MFMA16(a, b, c) __builtin_amdgcn_mfma_f32_16x16x32_bf16((a), (b), (c), 0, 0, 0)

__device__ __forceinline__ u16 f2bf(float f) {
  union { float f; unsigned u; } v; v.f = f;
  unsigned r = (v.u + 0x7fffu + ((v.u >> 16) & 1u)) >> 16;
  return (u16)r;
}
__device__ __forceinline__ float sigm(float x) { return 1.f / (1.f + __expf(-x)); }
__device__ __forceinline__ float tanh_f(float x) { return 1.f - 2.f / (1.f + __expf(2.f * x)); }

// ---------------------------------------------------------------- xcvt: x fp32 -> xb bf16 + row stats
// 2048 blocks x 256 thr = 8192 waves; each wave: 32 rows, 4 rows in flight.
__global__ __launch_bounds__(256, 4) void xcvt_kernel(
    const float* __restrict__ x, u16* __restrict__ xb, float2* __restrict__ stats2) {
  const int lane = threadIdx.x & 63;
  const int gw = blockIdx.x * 4 + (threadIdx.x >> 6);  // 0..8191
#pragma unroll 1
  for (int it = 0; it < 8; it++) {
    float4 v[4];
    int r[4];
#pragma unroll
    for (int j = 0; j < 4; j++) {
      r[j] = (it * 4 + j) * 8192 + gw;
      v[j] = *reinterpret_cast<const float4*>(x + (size_t)r[j] * 256 + lane * 4);
    }
#pragma unroll
    for (int j = 0; j < 4; j++) {
      float4 vv = v[j];
      float s = vv.x + vv.y + vv.z + vv.w;
      float sq = vv.x * vv.x + vv.y * vv.y + vv.z * vv.z + vv.w * vv.w;
#pragma unroll
      for (int m = 1; m < 64; m <<= 1) { s += __shfl_xor(s, m); sq += __shfl_xor(sq, m); }
      float mu = s * (1.f / 256.f);
      float var = sq * (1.f / 256.f) - mu * mu;
      float rstd = rsqrtf(fmaxf(var, 0.f) + 1e-5f);
      if (lane == 0) stats2[r[j]] = make_float2(rstd, rstd * mu);
      unsigned lo = (unsigned)f2bf(vv.x) | ((unsigned)f2bf(vv.y) << 16);
      unsigned hi = (unsigned)f2bf(vv.z) | ((unsigned)f2bf(vv.w) << 16);
      *reinterpret_cast<uint2*>(xb + (size_t)r[j] * 256 + lane * 4) = make_uint2(lo, hi);
    }
  }
}

// ---------------------------------------------------------------- prep: LDS-tiled transpose + casts
__global__ __launch_bounds__(256) void prep_kernel(
    const float* __restrict__ Wq, const float* __restrict__ Wk, const float* __restrict__ Wv,
    const float* __restrict__ wih, const float* __restrict__ whh,
    const float* __restrict__ w1, const float* __restrict__ w2,
    u16* __restrict__ wkB, u16* __restrict__ wqT, u16* __restrict__ wvT,
    u16* __restrict__ wihB, u16* __restrict__ whhB, u16* __restrict__ w1T, u16* __restrict__ w2T) {
  const int bid = blockIdx.x;
  const int tid = threadIdx.x;
  if (bid < 160) {
    __shared__ float tile[64][65];
    const float* src; u16* dst; int R, C, t;
    if (bid < 16)      { src = Wq; dst = wqT; R = 256;  C = 256;  t = bid; }
    else if (bid < 32) { src = Wv; dst = wvT; R = 256;  C = 256;  t = bid - 16; }
    else if (bid < 96) { src = w1; dst = w1T; R = 1024; C = 256;  t = bid - 32; }
    else               { src = w2; dst = w2T; R = 256;  C = 1024; t = bid - 96; }
    const int tilesJ = C >> 6;
    const int i0 = (t / tilesJ) * 64, j0 = (t % tilesJ) * 64;
    const int c = tid & 63, r0 = tid >> 6;
#pragma unroll
    for (int rr = 0; rr < 16; rr++) {
      int row = rr * 4 + r0;
      tile[row][c] = src[(size_t)(j0 + row) * R + i0 + c];
    }
    __syncthreads();
#pragma unroll
    for (int rr = 0; rr < 16; rr++) {
      int row = rr * 4 + r0;
      dst[(size_t)(i0 + row) * C + j0 + c] = f2bf(tile[c][row]);
    }
  } else {
    int gid = (bid - 160) * 256 + tid;
    for (int i4 = gid; i4 < 114688; i4 += 64 * 256) {
      int i = i4 * 4;
      const float* s; u16* d; int off;
      if (i < 65536) { s = Wk; d = wkB; off = i; }
      else if (i < 262144) { s = wih; d = wihB; off = i - 65536; }
      else { s = whh; d = whhB; off = i - 262144; }
      float4 v = *reinterpret_cast<const float4*>(s + off);
      unsigned lo = (unsigned)f2bf(v.x) | ((unsigned)f2bf(v.y) << 16);
      unsigned hi = (unsigned)f2bf(v.z) | ((unsigned)f2bf(v.w) << 16);
      *reinterpret_cast<uint2*>(d + off) = make_uint2(lo, hi);
    }
  }
}

// ---------------------------------------------------------------- per-wave LN of one row, rows 8..15 zeroed
__device__ __forceinline__ void ln_row16(const float (*src)[264], u16 (*dst)[264],
                                         const float* __restrict__ g, const float* __restrict__ bb,
                                         int wave, int lane) {
  int row = wave;
  if (row < 8) {
    float4 v = *reinterpret_cast<const float4*>(&src[row][lane * 4]);
    float s = v.x + v.y + v.z + v.w;
    float sq = v.x * v.x + v.y * v.y + v.z * v.z + v.w * v.w;
#pragma unroll
    for (int m = 1; m < 64; m <<= 1) { s += __shfl_xor(s, m); sq += __shfl_xor(sq, m); }
    float mu = s * (1.f / 256.f);
    float var = sq * (1.f / 256.f) - mu * mu;
    float rstd = rsqrtf(fmaxf(var, 0.f) + 1e-5f);
    float4 gg = *reinterpret_cast<const float4*>(&g[lane * 4]);
    float4 bv = *reinterpret_cast<const float4*>(&bb[lane * 4]);
    unsigned lo = (unsigned)f2bf((v.x - mu) * rstd * gg.x + bv.x) |
                  ((unsigned)f2bf((v.y - mu) * rstd * gg.y + bv.y) << 16);
    unsigned hi = (unsigned)f2bf((v.z - mu) * rstd * gg.z + bv.z) |
                  ((unsigned)f2bf((v.w - mu) * rstd * gg.w + bv.w) << 16);
    *reinterpret_cast<uint2*>(&dst[row][lane * 4]) = make_uint2(lo, hi);
  } else if (row < 16) {
    *reinterpret_cast<uint2*>(&dst[row][lane * 4]) = make_uint2(0, 0);
  }
}

// ---------------------------------------------------------------- slot kernel: one block (1024 thr, 16 waves) per batch
__global__ __launch_bounds__(1024, 4) void slot_kernel(
    float* __restrict__ slots, u16* __restrict__ qg, float* __restrict__ cd,
    const float* __restrict__ wsY, const float* __restrict__ wsS,
    const u16* __restrict__ wvT, const u16* __restrict__ wihB, const u16* __restrict__ whhB,
    const u16* __restrict__ w1T, const u16* __restrict__ w2T, const u16* __restrict__ wqT,
    const u16* __restrict__ wkB,
    const float* __restrict__ bih, const float* __restrict__ bhh,
    const float* __restrict__ b1v, const float* __restrict__ b2v,
    const float* __restrict__ g_in, const float* __restrict__ b_in,
    const float* __restrict__ g_s, const float* __restrict__ b_s,
    const float* __restrict__ g_m, const float* __restrict__ b_m,
    const float* __restrict__ s_mu, const float* __restrict__ s_ls,
    const float* __restrict__ noise,
    float* __restrict__ d_out, int do_update) {
  __shared__ alignas(16) char pool[58368];
  u16 (*h_lds)[1032] = reinterpret_cast<u16(*)[1032]>(pool);            // 33024 (P5->P6)
  u16 (*u_lds)[264] = reinterpret_cast<u16(*)[264]>(pool);              // alias h (P1->P2)
  u16 (*uv_lds)[264] = reinterpret_cast<u16(*)[264]>(pool + 8448);      // alias h (P2->P3)
  u16 (*sb_lds)[264] = reinterpret_cast<u16(*)[264]>(pool + 16896);     // alias h (P0->P3)
  u16 (*m_lds)[264] = reinterpret_cast<u16(*)[264]>(pool + 33024);      // 8448
  float (*ns_lds)[264] = reinterpret_cast<float(*)[264]>(pool + 41472); // 16896
  u16 (*q_lds)[264] = reinterpret_cast<u16(*)[264]>(pool + 41472);      // alias ns (P8->P9)
  __shared__ float sS0[16], sS1[16], sInv[16];
  __shared__ float redq[16][4][4][2];

  const int b = blockIdx.x;
  const int tid = threadIdx.x;
  const int lane = tid & 63, wave = tid >> 6;
  const int quad = lane >> 4, col = lane & 15;
  const int i256 = tid & 255, s4 = tid >> 8;
  const f32x4 vzero = {0.f, 0.f, 0.f, 0.f};

  if (do_update) {
    // P0: reduce S partials over 32 chunks; stage slots as bf16
    if (tid < 16) {
      float S0 = 0.f, S1 = 0.f;
      if (tid < 8) {
        for (int c = 0; c < 32; c++) {
          S0 += wsS[((b * 32 + c) * 8 + tid) * 2 + 0];
          S1 += wsS[((b * 32 + c) * 8 + tid) * 2 + 1];
        }
      }
      sS0[tid] = S0; sS1[tid] = S1; sInv[tid] = 1.f / (S0 + 1e-8f);
    }
#pragma unroll
    for (int r = 0; r < 4; r++) {
      int s = s4 + r * 4;
      sb_lds[s][i256] = (s < 8) ? f2bf(slots[(size_t)(b * 8 + s) * 256 + i256]) : (u16)0;
    }
    __syncthreads();
    // P1: u_hat
    {
      float gv = g_in[i256], bv = b_in[i256];
#pragma unroll
      for (int r = 0; r < 4; r++) {
        int s = s4 + r * 4;
        if (s < 8) {
          float y = 0.f;
#pragma unroll
          for (int c = 0; c < 32; c++) y += wsY[((size_t)((b * 32 + c) * 8 + s)) * 256 + i256];
          u_lds[s][i256] = f2bf((gv * (y - sS1[s]) + bv * sS0[s]) * sInv[s]);
        } else {
          u_lds[s][i256] = 0;
        }
      }
    }
    __syncthreads();
    // P2: updates_v = u_hat @ Wv (one tile per wave)
    {
      bf16x8 af[8];
#pragma unroll
      for (int k = 0; k < 8; k++)
        af[k] = *reinterpret_cast<const bf16x8*>(&u_lds[col][k * 32 + quad * 8]);
      int ct = wave;
      f32x4 acc = vzero;
#pragma unroll
      for (int k = 0; k < 8; k++) {
        bf16x8 bf = *reinterpret_cast<const bf16x8*>(wvT + (size_t)(ct * 16 + col) * 256 + k * 32 + quad * 8);
        acc = MFMA16(af[k], bf, acc);
      }
#pragma unroll
      for (int r = 0; r < 4; r++) {
        int s = quad * 4 + r;
        uv_lds[s][ct * 16 + col] = (s < 8) ? f2bf(acc[r]) : (u16)0;
      }
    }
    __syncthreads();
    // P3: gi/gh GEMMs + GRU elementwise -> ns_lds (one d-tile per wave)
    {
      bf16x8 afu[8], afs[8];
#pragma unroll
      for (int k = 0; k < 8; k++) {
        afu[k] = *reinterpret_cast<const bf16x8*>(&uv_lds[col][k * 32 + quad * 8]);
        afs[k] = *reinterpret_cast<const bf16x8*>(&sb_lds[col][k * 32 + quad * 8]);
      }
      int d = wave * 16 + col;
      f32x4 a_ir = vzero, a_iz = vzero, a_in = vzero, a_hr = vzero, a_hz = vzero, a_hn = vzero;
#pragma unroll
      for (int k = 0; k < 8; k++) {
        int ko = k * 32 + quad * 8;
        a_ir = MFMA16(afu[k], *reinterpret_cast<const bf16x8*>(wihB + (size_t)(d)*256 + ko), a_ir);
        a_iz = MFMA16(afu[k], *reinterpret_cast<const bf16x8*>(wihB + (size_t)(256 + d) * 256 + ko), a_iz);
        a_in = MFMA16(afu[k], *reinterpret_cast<const bf16x8*>(wihB + (size_t)(512 + d) * 256 + ko), a_in);
        a_hr = MFMA16(afs[k], *reinterpret_cast<const bf16x8*>(whhB + (size_t)(d)*256 + ko), a_hr);
        a_hz = MFMA16(afs[k], *reinterpret_cast<const bf16x8*>(whhB + (size_t)(256 + d) * 256 + ko), a_hz);
        a_hn = MFMA16(afs[k], *reinterpret_cast<const bf16x8*>(whhB + (size_t)(512 + d) * 256 + ko), a_hn);
      }
      float bihr = bih[d], bihz = bih[256 + d], bihn = bih[512 + d];
      float bhhr = bhh[d], bhhz = bhh[256 + d], bhhn = bhh[512 + d];
#pragma unroll
      for (int r = 0; r < 4; r++) {
        int s = quad * 4 + r;
        float rg = sigm(a_ir[r] + bihr + a_hr[r] + bhhr);
        float zg = sigm(a_iz[r] + bihz + a_hz[r] + bhhz);
        float ng = tanh_f(a_in[r] + bihn + rg * (a_hn[r] + bhhn));
        float prev = (s < 8) ? slots[(size_t)(b * 8 + s) * 256 + d] : 0.f;
        float ns = (1.f - zg) * ng + zg * prev;
        ns_lds[s][d] = (s < 8) ? ns : 0.f;
      }
    }
    __syncthreads();
    // P4: LN_m -> m_lds
    ln_row16(ns_lds, m_lds, g_m, b_m, wave, lane);
    __syncthreads();
    // P5: mlp1 -> h_lds (relu), 4 tiles per wave
    {
      bf16x8 af[8];
#pragma unroll
      for (int k = 0; k < 8; k++)
        af[k] = *reinterpret_cast<const bf16x8*>(&m_lds[col][k * 32 + quad * 8]);
      for (int cc = 0; cc < 4; cc++) {
        int ct = wave * 4 + cc;
        f32x4 acc = vzero;
#pragma unroll
        for (int k = 0; k < 8; k++) {
          bf16x8 bf = *reinterpret_cast<const bf16x8*>(w1T + (size_t)(ct * 16 + col) * 256 + k * 32 + quad * 8);
          acc = MFMA16(af[k], bf, acc);
        }
        float bb = b1v[ct * 16 + col];
#pragma unroll
        for (int r = 0; r < 4; r++) {
          int s = quad * 4 + r;
          float h = fmaxf(acc[r] + bb, 0.f);
          h_lds[s][ct * 16 + col] = (s < 8) ? f2bf(h) : (u16)0;
        }
      }
    }
    __syncthreads();
    // P6: mlp2 + residual -> new slots (one tile per wave)
    {
      int ct = wave;
      f32x4 acc = vzero;
      for (int k = 0; k < 32; k++) {
        bf16x8 af = *reinterpret_cast<const bf16x8*>(&h_lds[col][k * 32 + quad * 8]);
        bf16x8 bf = *reinterpret_cast<const bf16x8*>(w2T + (size_t)(ct * 16 + col) * 1024 + k * 32 + quad * 8);
        acc = MFMA16(af, bf, acc);
      }
      int d = ct * 16 + col;
      float bb = b2v[d];
#pragma unroll
      for (int r = 0; r < 4; r++) {
        int s = quad * 4 + r;
        if (s < 8) {
          float fin = ns_lds[s][d] + acc[r] + bb;
          slots[(size_t)(b * 8 + s) * 256 + d] = fin;
          d_out[(size_t)(b * 8 + s) * 256 + d] = fin;
          ns_lds[s][d] = fin;
        }
      }
    }
    __syncthreads();
  } else {
    // init: slots = mu + exp(ls)*noise
#pragma unroll
    for (int r = 0; r < 4; r++) {
      int s = s4 + r * 4;
      float v = 0.f;
      if (s < 8) {
        v = s_mu[i256] + __expf(s_ls[i256]) * noise[(size_t)(b * 8 + s) * 256 + i256];
        slots[(size_t)(b * 8 + s) * 256 + i256] = v;
      }
      ns_lds[s][i256] = v;
    }
    __syncthreads();
  }

  // ---- TAIL: qg/cd for next attention pass ----
  ln_row16(ns_lds, m_lds, g_s, b_s, wave, lane);
  __syncthreads();
  // P8: q = s_n @ Wq -> q_lds (one tile per wave)
  {
    bf16x8 af[8];
#pragma unroll
    for (int k = 0; k < 8; k++)
      af[k] = *reinterpret_cast<const bf16x8*>(&m_lds[col][k * 32 + quad * 8]);
    int ct = wave;
    f32x4 acc = vzero;
#pragma unroll
    for (int k = 0; k < 8; k++) {
      bf16x8 bf = *reinterpret_cast<const bf16x8*>(wqT + (size_t)(ct * 16 + col) * 256 + k * 32 + quad * 8);
      acc = MFMA16(af[k], bf, acc);
    }
#pragma unroll
    for (int r = 0; r < 4; r++) {
      int s = quad * 4 + r;
      q_lds[s][ct * 16 + col] = (s < 8) ? f2bf(acc[r]) : (u16)0;
    }
  }
  __syncthreads();
  // P9: qk = q @ Wk-as-B; qg = g*qk/16; c = -sum qg; d = sum b*qk/16
  {
    bf16x8 af[8];
#pragma unroll
    for (int k = 0; k < 8; k++)
      af[k] = *reinterpret_cast<const bf16x8*>(&q_lds[col][k * 32 + quad * 8]);
    float cacc[4] = {0.f, 0.f, 0.f, 0.f}, dacc[4] = {0.f, 0.f, 0.f, 0.f};
    int ct = wave;
    f32x4 acc = vzero;
#pragma unroll
    for (int k = 0; k < 8; k++) {
      bf16x8 bf = *reinterpret_cast<const bf16x8*>(wkB + (size_t)(ct * 16 + col) * 256 + k * 32 + quad * 8);
      acc = MFMA16(af[k], bf, acc);
    }
    int i = ct * 16 + col;
    float gi_ = g_in[i] * 0.0625f, bi_ = b_in[i] * 0.0625f;
#pragma unroll
    for (int r = 0; r < 4; r++) {
      int s = quad * 4 + r;
      float qkv = acc[r];
      float qgv = (s < 8) ? gi_ * qkv : 0.f;
      qg[(size_t)(b * 16 + s) * 256 + i] = f2bf(qgv);
      cacc[r] -= qgv;
      dacc[r] += (s < 8) ? bi_ * qkv : 0.f;
    }
#pragma unroll
    for (int r = 0; r < 4; r++) {
#pragma unroll
      for (int m = 1; m < 16; m <<= 1) {
        cacc[r] += __shfl_xor(cacc[r], m);
        dacc[r] += __shfl_xor(dacc[r], m);
      }
    }
    if (col == 0) {
#pragma unroll
      for (int r = 0; r < 4; r++) {
        redq[wave][quad][r][0] = cacc[r];
        redq[wave][quad][r][1] = dacc[r];
      }
    }
    __syncthreads();
    if (tid < 16) {
      int qd = tid >> 2, r = tid & 3;
      float c = 0.f, dd = 0.f;
      for (int w = 0; w < 16; w++) { c += redq[w][qd][r][0]; dd += redq[w][qd][r][1]; }
      cd[(b * 16 + tid) * 2 + 0] = c;
      cd[(b * 16 + tid) * 2 + 1] = dd;
    }
  }
}

// ---------------------------------------------------------------- attention kernel (runs 3x, reads xb)
// grid (32 chunks, 64 batches), 256 threads (4 waves). 128 n's per block in 4 groups of 32.
// Double-buffered LDS staging, ONE barrier per group:
//   barrier -> issue loads g+1 -> phases on buf[g&1] -> store regs into buf[(g+1)&1]
__global__ __launch_bounds__(256, 3) void attn_kernel(
    const u16* __restrict__ xb, const float2* __restrict__ stats2,
    const u16* __restrict__ qg, const float* __restrict__ cd,
    float* __restrict__ out, float* __restrict__ wsY, float* __restrict__ wsS) {
  __shared__ alignas(16) u16 x_lds[2][32][280];   // pad 280: phase-A b128 2-way banks
  __shared__ alignas(16) u16 a2s[4][16][40];      // wave-private a2^T scratch
  __shared__ float2 stats_lds[2][32];

  const int chunk = blockIdx.x, b = blockIdx.y;
  const int tid = threadIdx.x;
  const int lane = tid & 63, wave = tid >> 6;   // 4 waves
  const int quad = lane >> 4, col = lane & 15;

  // hoisted per-block constants: qg fragments (phase-A B-operand) + per-slot scalars
  bf16x8 bfrag[8];
#pragma unroll
  for (int k = 0; k < 8; k++)
    bfrag[k] = *reinterpret_cast<const bf16x8*>(qg + (size_t)(b * 16 + col) * 256 + k * 32 + quad * 8);
  const float2 cdv = *reinterpret_cast<const float2*>(cd + (b * 16 + col) * 2);

  f32x4 Yacc[4];
#pragma unroll
  for (int cc = 0; cc < 4; cc++) Yacc[cc] = {0.f, 0.f, 0.f, 0.f};
  float s0a = 0.f, s1a = 0.f;
  float* out_attn = out + 131072;

  uint2 pf[8];
  float2 pfs;
  // pre-stage group 0 into buffer 0
  {
    const int nb0 = chunk * 128;
#pragma unroll
    for (int p = 0; p < 8; p++)
      pf[p] = *reinterpret_cast<const uint2*>(xb + (size_t)(b * 4096 + nb0 + wave * 8 + p) * 256 + lane * 4);
    if (tid < 32) pfs = stats2[(size_t)b * 4096 + nb0 + tid];
#pragma unroll
    for (int p = 0; p < 8; p++)
      *reinterpret_cast<uint2*>(&x_lds[0][wave * 8 + p][lane * 4]) = pf[p];
    if (tid < 32) stats_lds[0][tid] = pfs;
  }

  for (int g = 0; g < 4; g++) {
    const int cur = g & 1;
    const int nb = chunk * 128 + g * 32;
    __syncthreads();  // buf[cur] fully staged; buf[cur^1] free
    // ---- issue next group's loads (land during phases) ----
    if (g < 3) {
      const int nbn = nb + 32;
#pragma unroll
      for (int p = 0; p < 8; p++)
        pf[p] = *reinterpret_cast<const uint2*>(xb + (size_t)(b * 4096 + nbn + wave * 8 + p) * 256 + lane * 4);
      if (tid < 32) pfs = stats2[(size_t)b * 4096 + nbn + tid];
    }
    // ---- phase A (all waves, redundant): 2 row-tiles of 16 ----
#pragma unroll
    for (int t = 0; t < 2; t++) {
      bf16x8 af[8];
#pragma unroll
      for (int k = 0; k < 8; k++)
        af[k] = *reinterpret_cast<const bf16x8*>(&x_lds[cur][t * 16 + col][k * 32 + quad * 8]);
      f32x4 acc = {0.f, 0.f, 0.f, 0.f};
#pragma unroll
      for (int k = 0; k < 8; k++) acc = MFMA16(af[k], bfrag[k], acc);

      float at[4], rmx[4], rmy[4];
#pragma unroll
      for (int r = 0; r < 4; r++) {
        float2 rm = stats_lds[cur][t * 16 + quad * 4 + r];
        rmx[r] = rm.x; rmy[r] = rm.y;
        float lg = rm.x * acc[r] + rm.y * cdv.x + cdv.y;
        float mx = lg;
        mx = fmaxf(mx, __shfl_xor(mx, 1));
        mx = fmaxf(mx, __shfl_xor(mx, 2));
        mx = fmaxf(mx, __shfl_xor(mx, 4));
        float e = __expf(lg - mx);
        float sm = e;
        sm += __shfl_xor(sm, 1); sm += __shfl_xor(sm, 2); sm += __shfl_xor(sm, 4);
        at[r] = e / sm;
      }
      if (col < 8) {
#pragma unroll
        for (int r = 0; r < 4; r++)
          a2s[wave][col][t * 16 + quad * 4 + r] = f2bf(at[r] * rmx[r]);
        if (wave == 0) {
#pragma unroll
          for (int r = 0; r < 4; r++) {
            out_attn[(size_t)(b * 8 + col) * 4096 + nb + t * 16 + quad * 4 + r] = at[r];
            s0a += at[r];
            s1a += at[r] * rmy[r];
          }
        }
      }
    }
    // ---- phase B: Y[s][i] += a2^T @ x (wave-private scratch; garbage A-rows only hit garbage D-rows) ----
    {
      bf16x8 afa = *reinterpret_cast<const bf16x8*>(&a2s[wave][col][quad * 8]);
#pragma unroll
      for (int cc = 0; cc < 4; cc++) {
        const int ib = (wave * 4 + cc) * 16 + col;
        union { short s[8]; bf16x8 v; } bx;
#pragma unroll
        for (int j = 0; j < 8; j++) bx.s[j] = (short)x_lds[cur][quad * 8 + j][ib];
        Yacc[cc] = MFMA16(afa, bx.v, Yacc[cc]);
      }
    }
    // ---- store next group into the other buffer (vmcnt wait lands here, after compute) ----
    if (g < 3) {
#pragma unroll
      for (int p = 0; p < 8; p++)
        *reinterpret_cast<uint2*>(&x_lds[cur ^ 1][wave * 8 + p][lane * 4]) = pf[p];
      if (tid < 32) stats_lds[cur ^ 1][tid] = pfs;
    }
  }
  // ---- epilogue ----
  if (quad < 2) {
#pragma unroll
    for (int cc = 0; cc < 4; cc++) {
      int i = (wave * 4 + cc) * 16 + col;
#pragma unroll
      for (int r = 0; r < 4; r++) {
        int s = quad * 4 + r;
        wsY[(size_t)((b * 32 + chunk) * 8 + s) * 256 + i] = Yacc[cc][r];
      }
    }
  }
  s0a += __shfl_xor(s0a, 16); s0a += __shfl_xor(s0a, 32);
  s1a += __shfl_xor(s1a, 16); s1a += __shfl_xor(s1a, 32);
  if (wave == 0 && lane < 8) {
    wsS[((b * 32 + chunk) * 8 + lane) * 2 + 0] = s0a;
    wsS[((b * 32 + chunk) * 8 + lane) * 2 + 1] = s1a;
  }
}

// ---------------------------------------------------------------- launch
extern "C" void kernel_launch(void* const* d_in, const int* in_sizes, int n_in,
                              void* d_out, int out_size, void* d_ws, size_t ws_size,
                              hipStream_t stream) {
  const float* inputs = (const float*)d_in[0];
  const float* noise = (const float*)d_in[1];
  const float* s_mu = (const float*)d_in[2];
  const float* s_ls = (const float*)d_in[3];
  const float* g_in = (const float*)d_in[4];
  const float* b_in = (const float*)d_in[5];
  const float* g_s = (const float*)d_in[6];
  const float* b_s = (const float*)d_in[7];
  const float* g_m = (const float*)d_in[8];
  const float* b_m = (const float*)d_in[9];
  const float* Wq = (const float*)d_in[10];
  const float* Wk = (const float*)d_in[11];
  const float* Wv = (const float*)d_in[12];
  const float* wih = (const float*)d_in[13];
  const float* whh = (const float*)d_in[14];
  const float* bih = (const float*)d_in[15];
  const float* bhh = (const float*)d_in[16];
  const float* w1 = (const float*)d_in[17];
  const float* b1v = (const float*)d_in[18];
  const float* w2 = (const float*)d_in[19];
  const float* b2v = (const float*)d_in[20];
  float* out = (float*)d_out;

  size_t o = 0;
  auto take = [&](size_t bytes) {
    void* p = (char*)d_ws + o;
    o += (bytes + 255) & ~(size_t)255;
    return p;
  };
  float* slots = (float*)take((size_t)64 * 8 * 256 * 4);
  u16* qg = (u16*)take((size_t)64 * 16 * 256 * 2);
  float* cd = (float*)take((size_t)64 * 16 * 2 * 4);
  float* wsY = (float*)take((size_t)64 * 32 * 8 * 256 * 4);
  float* wsS = (float*)take((size_t)64 * 32 * 8 * 2 * 4);
  u16* wkB = (u16*)take((size_t)65536 * 2);
  u16* wqT = (u16*)take((size_t)65536 * 2);
  u16* wvT = (u16*)take((size_t)65536 * 2);
  u16* wihB = (u16*)take((size_t)196608 * 2);
  u16* whhB = (u16*)take((size_t)196608 * 2);
  u16* w1T = (u16*)take((size_t)262144 * 2);
  u16* w2T = (u16*)take((size_t)262144 * 2);
  u16* xb = (u16*)take((size_t)64 * 4096 * 256 * 2);
  float2* stats2 = (float2*)take((size_t)64 * 4096 * 8);

  prep_kernel<<<224, 256, 0, stream>>>(Wq, Wk, Wv, wih, whh, w1, w2,
                                       wkB, wqT, wvT, wihB, whhB, w1T, w2T);
  xcvt_kernel<<<2048, 256, 0, stream>>>(inputs, xb, stats2);
  slot_kernel<<<64, 1024, 0, stream>>>(slots, qg, cd, wsY, wsS,
                                       wvT, wihB, whhB, w1T, w2T, wqT, wkB,
                                       bih, bhh, b1v, b2v,
                                       g_in, b_in, g_s, b_s, g_m, b_m,
                                       s_mu, s_ls, noise, out, 0);
  for (int it = 0; it < 3; it++) {
    attn_kernel<<<dim3(32, 64), 256, 0, stream>>>(xb, stats2, qg, cd, out, wsY, wsS);
    slot_kernel<<<64, 1024, 0, stream>>>(slots, qg, cd, wsY, wsS,
                                         wvT, wihB, whhB, w1T, w2T, wqT, wkB,
                                         bih, bhh, b1v, b2v,
                                         g_in, b_in, g_s, b_s, g_m, b_m,
                                         s_mu, s_ls, noise, out, 1);
  }
}